// Round 7
// baseline (3276.364 us; speedup 1.0000x reference)
//
#include <hip/hip_runtime.h>

typedef unsigned int u32;
typedef unsigned long long u64;
typedef unsigned short u16;
typedef short s16x8 __attribute__((ext_vector_type(8)));
typedef float f32x4 __attribute__((ext_vector_type(4)));

namespace {
constexpr int kB = 16384, kL = 20;
constexpr int RPB = 64;

// packed split-bf16 weights in d_ws (u16 elems). per (kt,n): hi[32] | lo[32]
constexpr int OFF_A1 = 0;                       // 128x256
constexpr int OFF_A2 = OFF_A1 + 128 * 256 * 2;  // 256x256
constexpr int OFF_M1 = OFF_A2 + 256 * 256 * 2;  // 128x256
constexpr int OFF_M2 = OFF_M1 + 128 * 256 * 2;  // 256x256
constexpr int OFF_M3 = OFF_M2 + 256 * 256 * 2;  // 256x64
constexpr int OFF_U1 = OFF_M3 + 256 * 64 * 2;   // 64x64
constexpr int OFF_U2 = OFF_U1 + 64 * 64 * 2;    // 128x64
constexpr int OFF_U3 = OFF_U2 + 128 * 64 * 2;   // 64x64
constexpr int PACK_ELEMS = OFF_U3 + 64 * 64 * 2;   // 458752 u16 = 896 KB
constexpr size_t MSG_OFF = (size_t)PACK_ELEMS;     // u16 index
constexpr size_t WS_NEED = (MSG_OFF + (size_t)kB * kL * 64) * 2;  // ~42.9 MB

__device__ __forceinline__ u16 f2bf(float x) {
  u32 b = __builtin_bit_cast(u32, x);
  b += 0x7FFFu + ((b >> 16) & 1u);
  return (u16)(b >> 16);
}
__device__ __forceinline__ float bf2f(u16 h) {
  return __builtin_bit_cast(float, (u32)h << 16);
}
__device__ __forceinline__ void split2(float x, u16& hi, u16& lo) {
  hi = f2bf(x);
  lo = f2bf(x - bf2f(hi));
}
__device__ __forceinline__ f32x4 mfma16(s16x8 a, s16x8 b, f32x4 c) {
  return __builtin_amdgcn_mfma_f32_16x16x32_bf16(a, b, c, 0, 0, 0);
}
__device__ __forceinline__ s16x8 ldsf(const u16* p) {
  return *reinterpret_cast<const s16x8*>(p);
}
__device__ __forceinline__ int swz(int row, int idx) { return idx ^ ((row & 7) << 3); }

__device__ __forceinline__ float fast_rcp(float x) {
#if __has_builtin(__builtin_amdgcn_rcpf)
  return __builtin_amdgcn_rcpf(x);
#else
  return 1.0f / x;
#endif
}
__device__ __forceinline__ float tfast(float x) {  // tanh, |err| ~1e-6
#if __has_builtin(__builtin_amdgcn_exp2f)
  float e = __builtin_amdgcn_exp2f(x * 2.8853900817779268f);
#else
  float e = exp2f(x * 2.8853900817779268f);
#endif
  return fmaf(-2.0f, fast_rcp(e + 1.0f), 1.0f);
}

// split-bf16 tile accumulate: A (hi/lo) in LDS (XOR-swizzled), B packed global.
// NM row-tiles reuse each B fragment (12 MFMAs per 32-B load at NM=4).
template <int K, int LD, int N, int NT, int NM>
__device__ __forceinline__ void mm3m(const u16* __restrict__ AH, const u16* __restrict__ AL,
                                     const u16* __restrict__ Bp,
                                     int mbase, int c0, int r15, int g,
                                     f32x4 (&acc)[NM][NT]) {
  #pragma unroll
  for (int kt = 0; kt < K / 32; ++kt) {
    s16x8 bh[NT], bl[NT];
    #pragma unroll
    for (int nt = 0; nt < NT; ++nt) {
      const u16* bp = Bp + (size_t)(kt * N + c0 + nt * 16) * 64 + g * 8;
      bh[nt] = *reinterpret_cast<const s16x8*>(bp);
      bl[nt] = *reinterpret_cast<const s16x8*>(bp + 32);
    }
    #pragma unroll
    for (int m = 0; m < NM; ++m) {
      const int row = mbase + m * 16 + r15;
      const int off = swz(row, row * LD + kt * 32 + g * 8);
      s16x8 ah = ldsf(AH + off);
      s16x8 al = ldsf(AL + off);
      #pragma unroll
      for (int nt = 0; nt < NT; ++nt) {
        acc[m][nt] = mfma16(ah, bh[nt], acc[m][nt]);
        acc[m][nt] = mfma16(al, bh[nt], acc[m][nt]);
        acc[m][nt] = mfma16(ah, bl[nt], acc[m][nt]);
      }
    }
  }
}
}  // namespace

// ---------------- prep: pack weights into split-bf16 frag layout ----------------
__global__ __launch_bounds__(256) void prep_kernel(
    const float* __restrict__ aW1, const float* __restrict__ aW2,
    const float* __restrict__ mW1, const float* __restrict__ mW2,
    const float* __restrict__ mW3, const float* __restrict__ uW1,
    const float* __restrict__ uW2, const float* __restrict__ uW3,
    u16* __restrict__ ws) {
  const float* Ws[8] = {aW1, aW2, mW1, mW2, mW3, uW1, uW2, uW3};
  const int Ns[8]  = {256, 256, 256, 256, 64, 64, 64, 64};
  const int dst[8] = {OFF_A1, OFF_A2, OFF_M1, OFF_M2, OFF_M3, OFF_U1, OFF_U2, OFF_U3};
  const int cnt[8] = {32768, 65536, 32768, 65536, 16384, 4096, 8192, 4096};
  const int total = 229376;
  for (int e = blockIdx.x * 256 + threadIdx.x; e < total; e += gridDim.x * 256) {
    int l = 0, base = 0;
    while (e - base >= cnt[l]) { base += cnt[l]; ++l; }
    const int s = e - base, N = Ns[l];
    const int k = s / N, n = s % N;
    u16 hi, lo;
    split2(Ws[l][s], hi, lo);
    const int ob = dst[l] + ((k >> 5) * N + n) * 64 + (k & 31);
    ws[ob] = hi;
    ws[ob + 32] = lo;
  }
}

// ------- monolith: RPB=64, 16 waves, NM=4 B-reuse, msgs in global ws -------
__global__ __launch_bounds__(1024, 4) void actor_kernel(
    const float* __restrict__ state,
    const float* __restrict__ ub1, const float* __restrict__ ub2,
    const float* __restrict__ ub3,
    const float* __restrict__ ab1, const float* __restrict__ ab2,
    const float* __restrict__ aW3, const float* __restrict__ ab3,
    const float* __restrict__ mb1, const float* __restrict__ mb2,
    const float* __restrict__ mb3,
    const u16* __restrict__ wsp, u16* __restrict__ msgs,
    float* __restrict__ out) {
  __shared__ __align__(16) u16 lds[81920];   // 160 KB exactly
  u16* XMH = lds;             // 64x128  [0, 8192)
  u16* XML = lds + 8192;      //         [8192, 16384)
  u16* B1H = lds + 16384;     // 64x256  [16384, 32768)
  u16* B1L = lds + 32768;     //         [32768, 49152)
  u16* B2H = lds + 49152;     // 64x256  [49152, 65536)
  u16* B2L = lds + 65536;     //         [65536, 81920)
  // BU aliases (inside B1H / B2H regions):
  u16* XSH = B1H;                                   // 64x64
  u16* XSL = B1H + 4096;                            // 64x64
  float* SMCbu = reinterpret_cast<float*>(B2H);     // 64x64 f32 (16 KB = 8192 u16)
  u16* H2H = B2H + 8192;                            // 64x64
  u16* H2L = B2H + 12288;                           // 64x64
  // TD alias (B1 dead after M2):
  float* SMCtd = reinterpret_cast<float*>(B1H);     // 64x64 f32

  const int tid = threadIdx.x;
  const int wv = tid >> 6, lane = tid & 63;
  const int r15 = lane & 15, g = lane >> 4;
  const int nq = wv & 3, mh = wv >> 2;        // BU: 4 col-tiles x 4 row-tiles
  const int nr = tid >> 4, np = tid & 15;     // 64 rows x 16 lanes
  const int rowBase = blockIdx.x * RPB;
  const int c256 = wv * 16 + r15;             // TD: wave owns 16 cols
  const int c64 = nq * 16 + r15;

  const float ub1v = ub1[c64], ub2v = ub2[c64], ub3v = ub3[c64], mb3v = mb3[c64];
  const float ab1v = ab1[c256], ab2v = ab2[c256];
  const float mb1v = mb1[c256], mb2v = mb2[c256];
  const float ab3v = ab3[0];
  float aw3r[16];
  #pragma unroll
  for (int j = 0; j < 16; ++j) aw3r[j] = aW3[np * 16 + j];

  // zero xm planes (m-half must be 0; mu-half rewritten before use)
  for (int i = tid; i < 8192; i += 1024) { XMH[i] = 0; XML[i] = 0; }
  {  // stage state(t=19) -> XS planes
    const int c = np * 4;
    f32x4 v = *reinterpret_cast<const f32x4*>(
        state + ((size_t)(rowBase + nr) * kL + (kL - 1)) * 64 + c);
    u16 h[4], l[4];
    #pragma unroll
    for (int j = 0; j < 4; ++j) split2(v[j], h[j], l[j]);
    const int o = swz(nr, nr * 64 + c);
    *(u32*)&XSH[o] = (u32)h[0] | ((u32)h[1] << 16);
    *(u32*)&XSH[o + 2] = (u32)h[2] | ((u32)h[3] << 16);
    *(u32*)&XSL[o] = (u32)l[0] | ((u32)l[1] << 16);
    *(u32*)&XSL[o + 2] = (u32)l[2] | ((u32)l[3] << 16);
  }
  __syncthreads();

  // ---------------- bottom-up: t = 19..0 ----------------
  for (int t = kL - 1; t >= 0; --t) {
    {  // s1: U1 -> SMCbu
      f32x4 acc[1][1] = {};
      mm3m<64, 64, 64, 1, 1>(XSH, XSL, wsp + OFF_U1, mh * 16, c64, r15, g, acc);
      #pragma unroll
      for (int i = 0; i < 4; ++i)
        SMCbu[(mh * 16 + g * 4 + i) * 64 + c64] = acc[0][0][i] + ub1v;
    }
    __syncthreads();
    {  // s2: normalize + tanh -> XM[0:64]
      f32x4 v = *reinterpret_cast<const f32x4*>(SMCbu + nr * 64 + np * 4);
      float ss = v[0]*v[0] + v[1]*v[1] + v[2]*v[2] + v[3]*v[3];
      ss += __shfl_xor(ss, 8); ss += __shfl_xor(ss, 4);
      ss += __shfl_xor(ss, 2); ss += __shfl_xor(ss, 1);
      const float inv = 1.f / fmaxf(sqrtf(ss), 1e-12f);
      u16 h[4], l[4];
      #pragma unroll
      for (int j = 0; j < 4; ++j) split2(tfast(v[j] * inv), h[j], l[j]);
      const int o = swz(nr, nr * 128 + np * 4);
      *(u32*)&XMH[o] = (u32)h[0] | ((u32)h[1] << 16);
      *(u32*)&XMH[o + 2] = (u32)h[2] | ((u32)h[3] << 16);
      *(u32*)&XML[o] = (u32)l[0] | ((u32)l[1] << 16);
      *(u32*)&XML[o + 2] = (u32)l[2] | ((u32)l[3] << 16);
    }
    __syncthreads();
    {  // s3: U2 (K=128) -> tanh -> H2 ; fold: stage state(t-1) -> XS
      f32x4 acc[1][1] = {};
      mm3m<128, 128, 64, 1, 1>(XMH, XML, wsp + OFF_U2, mh * 16, c64, r15, g, acc);
      #pragma unroll
      for (int i = 0; i < 4; ++i) {
        u16 h, l;
        split2(tfast(acc[0][0][i] + ub2v), h, l);
        const int row = mh * 16 + g * 4 + i;
        const int o = swz(row, row * 64 + c64);
        H2H[o] = h; H2L[o] = l;
      }
      if (t > 0) {
        const int c = np * 4;
        f32x4 v = *reinterpret_cast<const f32x4*>(
            state + ((size_t)(rowBase + nr) * kL + (t - 1)) * 64 + c);
        u16 h[4], l[4];
        #pragma unroll
        for (int j = 0; j < 4; ++j) split2(v[j], h[j], l[j]);
        const int o = swz(nr, nr * 64 + c);
        *(u32*)&XSH[o] = (u32)h[0] | ((u32)h[1] << 16);
        *(u32*)&XSH[o + 2] = (u32)h[2] | ((u32)h[3] << 16);
        *(u32*)&XSL[o] = (u32)l[0] | ((u32)l[1] << 16);
        *(u32*)&XSL[o + 2] = (u32)l[2] | ((u32)l[3] << 16);
      }
    }
    __syncthreads();
    {  // s4: U3 -> SMCbu
      f32x4 acc[1][1] = {};
      mm3m<64, 64, 64, 1, 1>(H2H, H2L, wsp + OFF_U3, mh * 16, c64, r15, g, acc);
      #pragma unroll
      for (int i = 0; i < 4; ++i)
        SMCbu[(mh * 16 + g * 4 + i) * 64 + c64] = acc[0][0][i] + ub3v;
    }
    __syncthreads();
    {  // s5: normalize -> msg (global, NT) ; XM[64:] = split(tanh(msg))
      f32x4 v = *reinterpret_cast<const f32x4*>(SMCbu + nr * 64 + np * 4);
      float ss = v[0]*v[0] + v[1]*v[1] + v[2]*v[2] + v[3]*v[3];
      ss += __shfl_xor(ss, 8); ss += __shfl_xor(ss, 4);
      ss += __shfl_xor(ss, 2); ss += __shfl_xor(ss, 1);
      const float inv = 1.f / fmaxf(sqrtf(ss), 1e-12f);
      float m[4];
      #pragma unroll
      for (int j = 0; j < 4; ++j) m[j] = v[j] * inv;
      const u64 w = (u64)f2bf(m[0]) | ((u64)f2bf(m[1]) << 16) |
                    ((u64)f2bf(m[2]) << 32) | ((u64)f2bf(m[3]) << 48);
      __builtin_nontemporal_store(
          w, (u64*)(msgs + ((size_t)(rowBase + nr) * kL + t) * 64 + np * 4));
      u16 h[4], l[4];
      #pragma unroll
      for (int j = 0; j < 4; ++j) split2(tfast(m[j]), h[j], l[j]);
      const int o = swz(nr, nr * 128 + 64 + np * 4);
      *(u32*)&XMH[o] = (u32)h[0] | ((u32)h[1] << 16);
      *(u32*)&XMH[o + 2] = (u32)h[2] | ((u32)h[3] << 16);
      *(u32*)&XML[o] = (u32)l[0] | ((u32)l[1] << 16);
      *(u32*)&XML[o + 2] = (u32)l[2] | ((u32)l[3] << 16);
    }
    __syncthreads();
  }

  // ---- pre-TD: m = 0 ; xm[0:64] = tanh(msg_0) ----
  {
    for (int i = tid; i < 4096; i += 1024) {
      const int row = i >> 6, c = i & 63;
      const int o = swz(row, row * 128 + 64 + c);
      XMH[o] = 0; XML[o] = 0;
    }
    const u64 w = __builtin_nontemporal_load(
        (const u64*)(msgs + ((size_t)(rowBase + nr) * kL + 0) * 64 + np * 4));
    u16 h[4], l[4];
    #pragma unroll
    for (int j = 0; j < 4; ++j)
      split2(tfast(bf2f((u16)(w >> (16 * j)))), h[j], l[j]);
    const int o = swz(nr, nr * 128 + np * 4);
    *(u32*)&XMH[o] = (u32)h[0] | ((u32)h[1] << 16);
    *(u32*)&XMH[o + 2] = (u32)h[2] | ((u32)h[3] << 16);
    *(u32*)&XML[o] = (u32)l[0] | ((u32)l[1] << 16);
    *(u32*)&XML[o + 2] = (u32)l[2] | ((u32)l[3] << 16);
  }
  __syncthreads();

  // ---------------- top-down: t = 0..19 ----------------
  for (int t = 0; t < kL; ++t) {
    {  // p1: A1 -> B1 (relu)
      f32x4 acc[4][1] = {};
      mm3m<128, 128, 256, 1, 4>(XMH, XML, wsp + OFF_A1, 0, c256, r15, g, acc);
      #pragma unroll
      for (int m = 0; m < 4; ++m)
        #pragma unroll
        for (int i = 0; i < 4; ++i) {
          const int row = m * 16 + g * 4 + i;
          u16 h, l;
          split2(fmaxf(acc[m][0][i] + ab1v, 0.f), h, l);
          const int o = swz(row, row * 256 + c256);
          B1H[o] = h; B1L[o] = l;
        }
    }
    __syncthreads();
    {  // p2: A2 -> B2 (relu)
      f32x4 acc[4][1] = {};
      mm3m<256, 256, 256, 1, 4>(B1H, B1L, wsp + OFF_A2, 0, c256, r15, g, acc);
      #pragma unroll
      for (int m = 0; m < 4; ++m)
        #pragma unroll
        for (int i = 0; i < 4; ++i) {
          const int row = m * 16 + g * 4 + i;
          u16 h, l;
          split2(fmaxf(acc[m][0][i] + ab2v, 0.f), h, l);
          const int o = swz(row, row * 256 + c256);
          B2H[o] = h; B2L[o] = l;
        }
    }
    __syncthreads();
    {  // p3: a3 (B2 -> out) + M1 (XM -> B1, relu)
      const int o0 = swz(nr, nr * 256 + np * 16);
      const int o1 = swz(nr, nr * 256 + np * 16 + 8);
      s16x8 h0 = ldsf(B2H + o0), h1 = ldsf(B2H + o1);
      s16x8 l0 = ldsf(B2L + o0), l1 = ldsf(B2L + o1);
      float sum = 0.f;
      #pragma unroll
      for (int j = 0; j < 8; ++j) {
        sum += (bf2f((u16)h0[j]) + bf2f((u16)l0[j])) * aw3r[j];
        sum += (bf2f((u16)h1[j]) + bf2f((u16)l1[j])) * aw3r[8 + j];
      }
      sum += __shfl_xor(sum, 8); sum += __shfl_xor(sum, 4);
      sum += __shfl_xor(sum, 2); sum += __shfl_xor(sum, 1);
      if (np == 0) out[(size_t)(rowBase + nr) * kL + t] = tfast(sum + ab3v);

      f32x4 acc[4][1] = {};
      mm3m<128, 128, 256, 1, 4>(XMH, XML, wsp + OFF_M1, 0, c256, r15, g, acc);
      #pragma unroll
      for (int m = 0; m < 4; ++m)
        #pragma unroll
        for (int i = 0; i < 4; ++i) {
          const int row = m * 16 + g * 4 + i;
          u16 h, l;
          split2(fmaxf(acc[m][0][i] + mb1v, 0.f), h, l);
          const int o = swz(row, row * 256 + c256);
          B1H[o] = h; B1L[o] = l;
        }
    }
    __syncthreads();
    {  // p4: M2 -> B2 (relu) ; fold: xm[0:64] = tanh(msg_{t+1}) from global
      u64 w = 0;
      if (t < kL - 1)
        w = __builtin_nontemporal_load(
            (const u64*)(msgs + ((size_t)(rowBase + nr) * kL + (t + 1)) * 64 + np * 4));
      f32x4 acc[4][1] = {};
      mm3m<256, 256, 256, 1, 4>(B1H, B1L, wsp + OFF_M2, 0, c256, r15, g, acc);
      #pragma unroll
      for (int m = 0; m < 4; ++m)
        #pragma unroll
        for (int i = 0; i < 4; ++i) {
          const int row = m * 16 + g * 4 + i;
          u16 h, l;
          split2(fmaxf(acc[m][0][i] + mb2v, 0.f), h, l);
          const int o = swz(row, row * 256 + c256);
          B2H[o] = h; B2L[o] = l;
        }
      if (t < kL - 1) {
        u16 h[4], l[4];
        #pragma unroll
        for (int j = 0; j < 4; ++j)
          split2(tfast(bf2f((u16)(w >> (16 * j)))), h[j], l[j]);
        const int o = swz(nr, nr * 128 + np * 4);
        *(u32*)&XMH[o] = (u32)h[0] | ((u32)h[1] << 16);
        *(u32*)&XMH[o + 2] = (u32)h[2] | ((u32)h[3] << 16);
        *(u32*)&XML[o] = (u32)l[0] | ((u32)l[1] << 16);
        *(u32*)&XML[o + 2] = (u32)l[2] | ((u32)l[3] << 16);
      }
    }
    __syncthreads();
    {  // p5: M3 -> SMCtd (aliases B1, dead after M2)
      f32x4 acc[1][1] = {};
      mm3m<256, 256, 64, 1, 1>(B2H, B2L, wsp + OFF_M3, mh * 16, c64, r15, g, acc);
      #pragma unroll
      for (int i = 0; i < 4; ++i)
        SMCtd[(mh * 16 + g * 4 + i) * 64 + c64] = acc[0][0][i] + mb3v;
    }
    __syncthreads();
    {  // p6: normalize -> m ; XM[64:] = split(tanh(m))
      f32x4 v = *reinterpret_cast<const f32x4*>(SMCtd + nr * 64 + np * 4);
      float ss = v[0]*v[0] + v[1]*v[1] + v[2]*v[2] + v[3]*v[3];
      ss += __shfl_xor(ss, 8); ss += __shfl_xor(ss, 4);
      ss += __shfl_xor(ss, 2); ss += __shfl_xor(ss, 1);
      const float inv = 1.f / fmaxf(sqrtf(ss), 1e-12f);
      u16 h[4], l[4];
      #pragma unroll
      for (int j = 0; j < 4; ++j) split2(tfast(v[j] * inv), h[j], l[j]);
      const int o = swz(nr, nr * 128 + 64 + np * 4);
      *(u32*)&XMH[o] = (u32)h[0] | ((u32)h[1] << 16);
      *(u32*)&XMH[o + 2] = (u32)h[2] | ((u32)h[3] << 16);
      *(u32*)&XML[o] = (u32)l[0] | ((u32)l[1] << 16);
      *(u32*)&XML[o + 2] = (u32)l[2] | ((u32)l[3] << 16);
    }
    __syncthreads();
  }
}

extern "C" void kernel_launch(void* const* d_in, const int* in_sizes, int n_in,
                              void* d_out, int out_size, void* d_ws, size_t ws_size,
                              hipStream_t stream) {
  (void)in_sizes; (void)n_in; (void)out_size;
  const float* state = (const float*)d_in[0];
  const float* uW1 = (const float*)d_in[1];
  const float* ub1 = (const float*)d_in[2];
  const float* uW2 = (const float*)d_in[3];
  const float* ub2 = (const float*)d_in[4];
  const float* uW3 = (const float*)d_in[5];
  const float* ub3 = (const float*)d_in[6];
  const float* aW1 = (const float*)d_in[7];
  const float* ab1 = (const float*)d_in[8];
  const float* aW2 = (const float*)d_in[9];
  const float* ab2 = (const float*)d_in[10];
  const float* aW3 = (const float*)d_in[11];
  const float* ab3 = (const float*)d_in[12];
  const float* mW1 = (const float*)d_in[13];
  const float* mb1 = (const float*)d_in[14];
  const float* mW2 = (const float*)d_in[15];
  const float* mb2 = (const float*)d_in[16];
  const float* mW3 = (const float*)d_in[17];
  const float* mb3 = (const float*)d_in[18];
  u16* wsp = (u16*)d_ws;
  float* out = (float*)d_out;

  if (ws_size < WS_NEED) return;
  u16* msgs = wsp + MSG_OFF;

  hipLaunchKernelGGL(prep_kernel, dim3(896), dim3(256), 0, stream,
                     aW1, aW2, mW1, mW2, mW3, uW1, uW2, uW3, wsp);
  hipLaunchKernelGGL(actor_kernel, dim3(kB / RPB), dim3(1024), 0, stream,
                     state, ub1, ub2, ub3, ab1, ab2, aW3, ab3,
                     mb1, mb2, mb3, wsp, msgs, out);
}

// Round 8
// 1399.771 us; speedup vs baseline: 2.3406x; 2.3406x over previous
//
#include <hip/hip_runtime.h>

typedef unsigned int u32;
typedef unsigned short u16;
typedef short s16x8 __attribute__((ext_vector_type(8)));
typedef float f32x4 __attribute__((ext_vector_type(4)));

namespace {
constexpr int kB = 16384, kL = 20;
constexpr int RPB = 32;

// packed split-bf16 weights in d_ws (u16 elems). per (kt,n): hi[32] | lo[32]
constexpr int OFF_A1 = 0;                       // 128x256
constexpr int OFF_A2 = OFF_A1 + 128 * 256 * 2;  // 256x256
constexpr int OFF_M1 = OFF_A2 + 256 * 256 * 2;  // 128x256
constexpr int OFF_M2 = OFF_M1 + 128 * 256 * 2;  // 256x256
constexpr int OFF_M3 = OFF_M2 + 256 * 256 * 2;  // 256x64
constexpr int OFF_U1 = OFF_M3 + 256 * 64 * 2;   // 64x64
constexpr int OFF_U2 = OFF_U1 + 64 * 64 * 2;    // 128x64
constexpr int OFF_U3 = OFF_U2 + 128 * 64 * 2;   // 64x64
constexpr int PACK_ELEMS = OFF_U3 + 64 * 64 * 2;  // 458752 u16 = 896 KB
constexpr size_t WS_NEED = (size_t)PACK_ELEMS * 2;

__device__ __forceinline__ u16 f2bf(float x) {
  u32 b = __builtin_bit_cast(u32, x);
  b += 0x7FFFu + ((b >> 16) & 1u);
  return (u16)(b >> 16);
}
__device__ __forceinline__ float bf2f(u16 h) {
  return __builtin_bit_cast(float, (u32)h << 16);
}
__device__ __forceinline__ void split2(float x, u16& hi, u16& lo) {
  hi = f2bf(x);
  lo = f2bf(x - bf2f(hi));
}
__device__ __forceinline__ f32x4 mfma16(s16x8 a, s16x8 b, f32x4 c) {
  return __builtin_amdgcn_mfma_f32_16x16x32_bf16(a, b, c, 0, 0, 0);
}
__device__ __forceinline__ s16x8 ldsf(const u16* p) {
  return *reinterpret_cast<const s16x8*>(p);
}
__device__ __forceinline__ int swz(int row, int idx) { return idx ^ ((row & 7) << 3); }

__device__ __forceinline__ float fast_rcp(float x) {
#if __has_builtin(__builtin_amdgcn_rcpf)
  return __builtin_amdgcn_rcpf(x);
#else
  return 1.0f / x;
#endif
}
__device__ __forceinline__ float tfast(float x) {  // tanh, |err| ~1e-6
#if __has_builtin(__builtin_amdgcn_exp2f)
  float e = __builtin_amdgcn_exp2f(x * 2.8853900817779268f);
#else
  float e = exp2f(x * 2.8853900817779268f);
#endif
  return fmaf(-2.0f, fast_rcp(e + 1.0f), 1.0f);
}

// B-fragment batch: ALL global loads for a phase issued before any MFMA.
template <int KT, int NT>
struct BF {
  s16x8 h[KT][NT], l[KT][NT];
};

template <int K, int N, int NT>
__device__ __forceinline__ void ldB(const u16* __restrict__ Bp, int c0, int g,
                                    BF<K / 32, NT>& f) {
  #pragma unroll
  for (int kt = 0; kt < K / 32; ++kt)
    #pragma unroll
    for (int nt = 0; nt < NT; ++nt) {
      const u16* bp = Bp + (kt * N + c0 + nt * 16) * 64 + g * 8;
      f.h[kt][nt] = ldsf(bp);
      f.l[kt][nt] = ldsf(bp + 32);
    }
}

// MFMA consume: A (hi/lo) from XOR-swizzled LDS, B from the preloaded batch.
template <int K, int LD, int NT, int NM>
__device__ __forceinline__ void mmB(const u16* __restrict__ AH,
                                    const u16* __restrict__ AL,
                                    const BF<K / 32, NT>& f,
                                    int mbase, int r15, int g,
                                    f32x4 (&acc)[NM][NT]) {
  #pragma unroll
  for (int kt = 0; kt < K / 32; ++kt)
    #pragma unroll
    for (int m = 0; m < NM; ++m) {
      const int row = mbase + m * 16 + r15;
      const int off = swz(row, row * LD + kt * 32 + g * 8);
      s16x8 ah = ldsf(AH + off);
      s16x8 al = ldsf(AL + off);
      #pragma unroll
      for (int nt = 0; nt < NT; ++nt) {
        acc[m][nt] = mfma16(ah, f.h[kt][nt], acc[m][nt]);
        acc[m][nt] = mfma16(al, f.h[kt][nt], acc[m][nt]);
        acc[m][nt] = mfma16(ah, f.l[kt][nt], acc[m][nt]);
      }
    }
}
}  // namespace

// ---------------- prep: pack weights into split-bf16 frag layout ----------------
__global__ __launch_bounds__(256) void prep_kernel(
    const float* __restrict__ aW1, const float* __restrict__ aW2,
    const float* __restrict__ mW1, const float* __restrict__ mW2,
    const float* __restrict__ mW3, const float* __restrict__ uW1,
    const float* __restrict__ uW2, const float* __restrict__ uW3,
    u16* __restrict__ ws) {
  const float* Ws[8] = {aW1, aW2, mW1, mW2, mW3, uW1, uW2, uW3};
  const int Ns[8]  = {256, 256, 256, 256, 64, 64, 64, 64};
  const int dst[8] = {OFF_A1, OFF_A2, OFF_M1, OFF_M2, OFF_M3, OFF_U1, OFF_U2, OFF_U3};
  const int cnt[8] = {32768, 65536, 32768, 65536, 16384, 4096, 8192, 4096};
  const int total = 229376;
  for (int e = blockIdx.x * 256 + threadIdx.x; e < total; e += gridDim.x * 256) {
    int l = 0, base = 0;
    while (e - base >= cnt[l]) { base += cnt[l]; ++l; }
    const int s = e - base, N = Ns[l];
    const int k = s / N, n = s % N;
    u16 hi, lo;
    split2(Ws[l][s], hi, lo);
    const int ob = dst[l] + ((k >> 5) * N + n) * 64 + (k & 31);
    ws[ob] = hi;
    ws[ob + 32] = lo;
  }
}

// ------- monolith: RPB=32, 8 waves, batched B-loads, full VGPR budget -------
__global__ __launch_bounds__(512) void actor_kernel(
    const float* __restrict__ state,
    const float* __restrict__ ub1, const float* __restrict__ ub2,
    const float* __restrict__ ub3,
    const float* __restrict__ ab1, const float* __restrict__ ab2,
    const float* __restrict__ aW3, const float* __restrict__ ab3,
    const float* __restrict__ mb1, const float* __restrict__ mb2,
    const float* __restrict__ mb3,
    const u16* __restrict__ wsp, float* __restrict__ out) {
  __shared__ __align__(16) u16 lds[81920];   // 160 KB exactly
  u16* XMH = lds;             // 32x128
  u16* XML = lds + 4096;
  u16* B1H = lds + 8192;      // 32x256
  u16* B1L = lds + 16384;
  u16* B2H = lds + 24576;     // 32x256
  u16* B2L = lds + 32768;
  u16* MSGS = lds + 40960;    // 32x20x64 (40 KB)
  // BU aliases:
  u16* XSH = B1H;             // 32x64
  u16* XSL = B1H + 2048;
  float* SMC = reinterpret_cast<float*>(B1L);  // 32x64 f32 (8 KB)
  u16* H2H = B2H;             // 32x64
  u16* H2L = B2H + 2048;

  const int tid = threadIdx.x;
  const int wv = tid >> 6, lane = tid & 63;
  const int r15 = lane & 15, g = lane >> 4;
  const int mh = wv >> 2, nq = wv & 3;     // 64-col layers: 2 row-halves x 4 col-tiles
  const int nr = tid >> 4, np = tid & 15;  // 32 rows x 16 lanes
  const int rowBase = blockIdx.x * RPB;
  const int c256 = wv * 32 + r15;          // 256-col layers: wave owns 32 cols (NT=2)
  const int c64 = nq * 16 + r15;

  const float ub1v = ub1[c64], ub2v = ub2[c64], ub3v = ub3[c64], mb3v = mb3[c64];
  const float ab3v = ab3[0];
  float aw3r[16];
  #pragma unroll
  for (int j = 0; j < 16; ++j) aw3r[j] = aW3[np * 16 + j];

  // zero m-half of xm planes
  for (int i = tid; i < 2048; i += 512) {
    const int row = i >> 6, c = i & 63;
    const int o = swz(row, row * 128 + 64 + c);
    XMH[o] = 0; XML[o] = 0;
  }
  {  // stage state(t=19)
    f32x4 v = *reinterpret_cast<const f32x4*>(
        state + ((size_t)(rowBase + nr) * kL + (kL - 1)) * 64 + np * 4);
    u16 h[4], l[4];
    #pragma unroll
    for (int j = 0; j < 4; ++j) split2(v[j], h[j], l[j]);
    const int o = swz(nr, nr * 64 + np * 4);
    *(u32*)&XSH[o] = (u32)h[0] | ((u32)h[1] << 16);
    *(u32*)&XSH[o + 2] = (u32)h[2] | ((u32)h[3] << 16);
    *(u32*)&XSL[o] = (u32)l[0] | ((u32)l[1] << 16);
    *(u32*)&XSL[o + 2] = (u32)l[2] | ((u32)l[3] << 16);
  }
  __syncthreads();

  // ---------------- bottom-up: t = 19..0 ----------------
  for (int t = kL - 1; t >= 0; --t) {
    {  // s1: U1 -> SMC raw
      BF<2, 1> f;
      ldB<64, 64, 1>(wsp + OFF_U1, c64, g, f);
      f32x4 acc[1][1] = {};
      mmB<64, 64, 1, 1>(XSH, XSL, f, mh * 16, r15, g, acc);
      #pragma unroll
      for (int i = 0; i < 4; ++i)
        SMC[(mh * 16 + g * 4 + i) * 64 + c64] = acc[0][0][i] + ub1v;
    }
    __syncthreads();
    {  // s2: normalize + tanh -> XM[0:64]
      f32x4 v = *reinterpret_cast<const f32x4*>(SMC + nr * 64 + np * 4);
      float ss = v[0]*v[0] + v[1]*v[1] + v[2]*v[2] + v[3]*v[3];
      ss += __shfl_xor(ss, 8); ss += __shfl_xor(ss, 4);
      ss += __shfl_xor(ss, 2); ss += __shfl_xor(ss, 1);
      const float inv = 1.f / fmaxf(sqrtf(ss), 1e-12f);
      u16 h[4], l[4];
      #pragma unroll
      for (int j = 0; j < 4; ++j) split2(tfast(v[j] * inv), h[j], l[j]);
      const int o = swz(nr, nr * 128 + np * 4);
      *(u32*)&XMH[o] = (u32)h[0] | ((u32)h[1] << 16);
      *(u32*)&XMH[o + 2] = (u32)h[2] | ((u32)h[3] << 16);
      *(u32*)&XML[o] = (u32)l[0] | ((u32)l[1] << 16);
      *(u32*)&XML[o + 2] = (u32)l[2] | ((u32)l[3] << 16);
    }
    __syncthreads();
    {  // s3: U2 (K=128) -> tanh -> H2 ; fold: stage state(t-1)
      BF<4, 1> f;
      ldB<128, 64, 1>(wsp + OFF_U2, c64, g, f);
      f32x4 vst = {};
      if (t > 0)
        vst = *reinterpret_cast<const f32x4*>(
            state + ((size_t)(rowBase + nr) * kL + (t - 1)) * 64 + np * 4);
      f32x4 acc[1][1] = {};
      mmB<128, 128, 1, 1>(XMH, XML, f, mh * 16, r15, g, acc);
      #pragma unroll
      for (int i = 0; i < 4; ++i) {
        u16 h, l;
        split2(tfast(acc[0][0][i] + ub2v), h, l);
        const int row = mh * 16 + g * 4 + i;
        const int o = swz(row, row * 64 + c64);
        H2H[o] = h; H2L[o] = l;
      }
      __syncthreads();
      if (t > 0) {
        u16 h[4], l[4];
        #pragma unroll
        for (int j = 0; j < 4; ++j) split2(vst[j], h[j], l[j]);
        const int o = swz(nr, nr * 64 + np * 4);
        *(u32*)&XSH[o] = (u32)h[0] | ((u32)h[1] << 16);
        *(u32*)&XSH[o + 2] = (u32)h[2] | ((u32)h[3] << 16);
        *(u32*)&XSL[o] = (u32)l[0] | ((u32)l[1] << 16);
        *(u32*)&XSL[o + 2] = (u32)l[2] | ((u32)l[3] << 16);
      }
    }
    __syncthreads();
    {  // s4: U3 -> SMC raw
      BF<2, 1> f;
      ldB<64, 64, 1>(wsp + OFF_U3, c64, g, f);
      f32x4 acc[1][1] = {};
      mmB<64, 64, 1, 1>(H2H, H2L, f, mh * 16, r15, g, acc);
      #pragma unroll
      for (int i = 0; i < 4; ++i)
        SMC[(mh * 16 + g * 4 + i) * 64 + c64] = acc[0][0][i] + ub3v;
    }
    __syncthreads();
    {  // s5: normalize -> msg (LDS) ; XM[64:] = split(tanh(msg))
      f32x4 v = *reinterpret_cast<const f32x4*>(SMC + nr * 64 + np * 4);
      float ss = v[0]*v[0] + v[1]*v[1] + v[2]*v[2] + v[3]*v[3];
      ss += __shfl_xor(ss, 8); ss += __shfl_xor(ss, 4);
      ss += __shfl_xor(ss, 2); ss += __shfl_xor(ss, 1);
      const float inv = 1.f / fmaxf(sqrtf(ss), 1e-12f);
      float m[4];
      #pragma unroll
      for (int j = 0; j < 4; ++j) m[j] = v[j] * inv;
      const int mi = nr * (kL * 64) + t * 64 + np * 4;
      *(u32*)&MSGS[mi] = (u32)f2bf(m[0]) | ((u32)f2bf(m[1]) << 16);
      *(u32*)&MSGS[mi + 2] = (u32)f2bf(m[2]) | ((u32)f2bf(m[3]) << 16);
      u16 h[4], l[4];
      #pragma unroll
      for (int j = 0; j < 4; ++j) split2(tfast(m[j]), h[j], l[j]);
      const int o = swz(nr, nr * 128 + 64 + np * 4);
      *(u32*)&XMH[o] = (u32)h[0] | ((u32)h[1] << 16);
      *(u32*)&XMH[o + 2] = (u32)h[2] | ((u32)h[3] << 16);
      *(u32*)&XML[o] = (u32)l[0] | ((u32)l[1] << 16);
      *(u32*)&XML[o + 2] = (u32)l[2] | ((u32)l[3] << 16);
    }
    __syncthreads();
  }

  // ---- pre-TD: m = 0 ; xm[0:64] = tanh(MSGS[0]) ----
  {
    for (int i = tid; i < 2048; i += 512) {
      const int row = i >> 6, c = i & 63;
      const int o = swz(row, row * 128 + 64 + c);
      XMH[o] = 0; XML[o] = 0;
    }
    const u32 w0 = *(const u32*)&MSGS[nr * (kL * 64) + np * 4];
    const u32 w1 = *(const u32*)&MSGS[nr * (kL * 64) + np * 4 + 2];
    u16 h[4], l[4];
    split2(tfast(bf2f((u16)w0)), h[0], l[0]);
    split2(tfast(bf2f((u16)(w0 >> 16))), h[1], l[1]);
    split2(tfast(bf2f((u16)w1)), h[2], l[2]);
    split2(tfast(bf2f((u16)(w1 >> 16))), h[3], l[3]);
    const int o = swz(nr, nr * 128 + np * 4);
    *(u32*)&XMH[o] = (u32)h[0] | ((u32)h[1] << 16);
    *(u32*)&XMH[o + 2] = (u32)h[2] | ((u32)h[3] << 16);
    *(u32*)&XML[o] = (u32)l[0] | ((u32)l[1] << 16);
    *(u32*)&XML[o + 2] = (u32)l[2] | ((u32)l[3] << 16);
  }
  __syncthreads();

  // ---------------- top-down: t = 0..19 ----------------
  for (int t = 0; t < kL; ++t) {
    {  // p1: A1 -> B1 (relu)
      BF<4, 2> f;
      ldB<128, 256, 2>(wsp + OFF_A1, c256, g, f);
      f32x4 acc[2][2] = {};
      mmB<128, 128, 2, 2>(XMH, XML, f, 0, r15, g, acc);
      const float b0 = ab1[c256], b1 = ab1[c256 + 16];
      #pragma unroll
      for (int nt = 0; nt < 2; ++nt) {
        const int col = c256 + nt * 16;
        const float bb = nt ? b1 : b0;
        #pragma unroll
        for (int m = 0; m < 2; ++m)
          #pragma unroll
          for (int i = 0; i < 4; ++i) {
            const int row = m * 16 + g * 4 + i;
            u16 h, l;
            split2(fmaxf(acc[m][nt][i] + bb, 0.f), h, l);
            const int o = swz(row, row * 256 + col);
            B1H[o] = h; B1L[o] = l;
          }
      }
    }
    __syncthreads();
    {  // p2: A2 -> B2 (relu)
      BF<8, 2> f;
      ldB<256, 256, 2>(wsp + OFF_A2, c256, g, f);
      f32x4 acc[2][2] = {};
      mmB<256, 256, 2, 2>(B1H, B1L, f, 0, r15, g, acc);
      const float b0 = ab2[c256], b1 = ab2[c256 + 16];
      #pragma unroll
      for (int nt = 0; nt < 2; ++nt) {
        const int col = c256 + nt * 16;
        const float bb = nt ? b1 : b0;
        #pragma unroll
        for (int m = 0; m < 2; ++m)
          #pragma unroll
          for (int i = 0; i < 4; ++i) {
            const int row = m * 16 + g * 4 + i;
            u16 h, l;
            split2(fmaxf(acc[m][nt][i] + bb, 0.f), h, l);
            const int o = swz(row, row * 256 + col);
            B2H[o] = h; B2L[o] = l;
          }
      }
    }
    __syncthreads();
    {  // p3: a3 (B2 -> out) + M1 (XM -> B1, relu)
      BF<4, 2> f;
      ldB<128, 256, 2>(wsp + OFF_M1, c256, g, f);
      const int o0 = swz(nr, nr * 256 + np * 16);
      const int o1 = swz(nr, nr * 256 + np * 16 + 8);
      s16x8 h0 = ldsf(B2H + o0), h1 = ldsf(B2H + o1);
      s16x8 l0 = ldsf(B2L + o0), l1 = ldsf(B2L + o1);
      float sum = 0.f;
      #pragma unroll
      for (int j = 0; j < 8; ++j) {
        sum += (bf2f((u16)h0[j]) + bf2f((u16)l0[j])) * aw3r[j];
        sum += (bf2f((u16)h1[j]) + bf2f((u16)l1[j])) * aw3r[8 + j];
      }
      sum += __shfl_xor(sum, 8); sum += __shfl_xor(sum, 4);
      sum += __shfl_xor(sum, 2); sum += __shfl_xor(sum, 1);
      if (np == 0) out[(size_t)(rowBase + nr) * kL + t] = tfast(sum + ab3v);

      f32x4 acc[2][2] = {};
      mmB<128, 128, 2, 2>(XMH, XML, f, 0, r15, g, acc);
      const float b0 = mb1[c256], b1 = mb1[c256 + 16];
      #pragma unroll
      for (int nt = 0; nt < 2; ++nt) {
        const int col = c256 + nt * 16;
        const float bb = nt ? b1 : b0;
        #pragma unroll
        for (int m = 0; m < 2; ++m)
          #pragma unroll
          for (int i = 0; i < 4; ++i) {
            const int row = m * 16 + g * 4 + i;
            u16 h, l;
            split2(fmaxf(acc[m][nt][i] + bb, 0.f), h, l);
            const int o = swz(row, row * 256 + col);
            B1H[o] = h; B1L[o] = l;
          }
      }
    }
    __syncthreads();
    {  // p4: M2 -> B2 (relu) ; fold: xm[0:64] = tanh(MSGS[t+1])
      BF<8, 2> f;
      ldB<256, 256, 2>(wsp + OFF_M2, c256, g, f);
      f32x4 acc[2][2] = {};
      mmB<256, 256, 2, 2>(B1H, B1L, f, 0, r15, g, acc);
      const float b0 = mb2[c256], b1 = mb2[c256 + 16];
      #pragma unroll
      for (int nt = 0; nt < 2; ++nt) {
        const int col = c256 + nt * 16;
        const float bb = nt ? b1 : b0;
        #pragma unroll
        for (int m = 0; m < 2; ++m)
          #pragma unroll
          for (int i = 0; i < 4; ++i) {
            const int row = m * 16 + g * 4 + i;
            u16 h, l;
            split2(fmaxf(acc[m][nt][i] + bb, 0.f), h, l);
            const int o = swz(row, row * 256 + col);
            B2H[o] = h; B2L[o] = l;
          }
      }
      if (t < kL - 1) {
        const int mi = nr * (kL * 64) + (t + 1) * 64 + np * 4;
        const u32 w0 = *(const u32*)&MSGS[mi];
        const u32 w1 = *(const u32*)&MSGS[mi + 2];
        u16 h[4], l[4];
        split2(tfast(bf2f((u16)w0)), h[0], l[0]);
        split2(tfast(bf2f((u16)(w0 >> 16))), h[1], l[1]);
        split2(tfast(bf2f((u16)w1)), h[2], l[2]);
        split2(tfast(bf2f((u16)(w1 >> 16))), h[3], l[3]);
        const int o = swz(nr, nr * 128 + np * 4);
        *(u32*)&XMH[o] = (u32)h[0] | ((u32)h[1] << 16);
        *(u32*)&XMH[o + 2] = (u32)h[2] | ((u32)h[3] << 16);
        *(u32*)&XML[o] = (u32)l[0] | ((u32)l[1] << 16);
        *(u32*)&XML[o + 2] = (u32)l[2] | ((u32)l[3] << 16);
      }
    }
    __syncthreads();
    {  // p5: M3 -> SMC raw (B1 region dead after M2)
      BF<8, 1> f;
      ldB<256, 64, 1>(wsp + OFF_M3, c64, g, f);
      f32x4 acc[1][1] = {};
      mmB<256, 256, 1, 1>(B2H, B2L, f, mh * 16, r15, g, acc);
      #pragma unroll
      for (int i = 0; i < 4; ++i)
        SMC[(mh * 16 + g * 4 + i) * 64 + c64] = acc[0][0][i] + mb3v;
    }
    __syncthreads();
    {  // p6: normalize -> m ; XM[64:] = split(tanh(m))
      f32x4 v = *reinterpret_cast<const f32x4*>(SMC + nr * 64 + np * 4);
      float ss = v[0]*v[0] + v[1]*v[1] + v[2]*v[2] + v[3]*v[3];
      ss += __shfl_xor(ss, 8); ss += __shfl_xor(ss, 4);
      ss += __shfl_xor(ss, 2); ss += __shfl_xor(ss, 1);
      const float inv = 1.f / fmaxf(sqrtf(ss), 1e-12f);
      u16 h[4], l[4];
      #pragma unroll
      for (int j = 0; j < 4; ++j) split2(tfast(v[j] * inv), h[j], l[j]);
      const int o = swz(nr, nr * 128 + 64 + np * 4);
      *(u32*)&XMH[o] = (u32)h[0] | ((u32)h[1] << 16);
      *(u32*)&XMH[o + 2] = (u32)h[2] | ((u32)h[3] << 16);
      *(u32*)&XML[o] = (u32)l[0] | ((u32)l[1] << 16);
      *(u32*)&XML[o + 2] = (u32)l[2] | ((u32)l[3] << 16);
    }
    __syncthreads();
  }
}

extern "C" void kernel_launch(void* const* d_in, const int* in_sizes, int n_in,
                              void* d_out, int out_size, void* d_ws, size_t ws_size,
                              hipStream_t stream) {
  (void)in_sizes; (void)n_in; (void)out_size;
  const float* state = (const float*)d_in[0];
  const float* uW1 = (const float*)d_in[1];
  const float* ub1 = (const float*)d_in[2];
  const float* uW2 = (const float*)d_in[3];
  const float* ub2 = (const float*)d_in[4];
  const float* uW3 = (const float*)d_in[5];
  const float* ub3 = (const float*)d_in[6];
  const float* aW1 = (const float*)d_in[7];
  const float* ab1 = (const float*)d_in[8];
  const float* aW2 = (const float*)d_in[9];
  const float* ab2 = (const float*)d_in[10];
  const float* aW3 = (const float*)d_in[11];
  const float* ab3 = (const float*)d_in[12];
  const float* mW1 = (const float*)d_in[13];
  const float* mb1 = (const float*)d_in[14];
  const float* mW2 = (const float*)d_in[15];
  const float* mb2 = (const float*)d_in[16];
  const float* mW3 = (const float*)d_in[17];
  const float* mb3 = (const float*)d_in[18];
  u16* wsp = (u16*)d_ws;
  float* out = (float*)d_out;

  if (ws_size < WS_NEED) return;

  hipLaunchKernelGGL(prep_kernel, dim3(896), dim3(256), 0, stream,
                     aW1, aW2, mW1, mW2, mW3, uW1, uW2, uW3, wsp);
  hipLaunchKernelGGL(actor_kernel, dim3(kB / RPB), dim3(512), 0, stream,
                     state, ub1, ub2, ub3, ab1, ab2, aW3, ab3,
                     mb1, mb2, mb3, wsp, out);
}